// Round 3
// baseline (2841.637 us; speedup 1.0000x reference)
//
#include <hip/hip_runtime.h>
#include <cmath>

#define NLVL 16
#define TPB 256
#define NBLOCKS 1536   // 6 blocks/CU x 256 CUs: single resident generation (no
                       // block replacement -> chip sweeps levels in loose lockstep,
                       // keeping one 4MB hashed table L2-resident at a time)

struct LevelCfg { float scale; unsigned offset; unsigned res; unsigned hashed; };
struct Cfg { LevelCfg lv[NLVL]; unsigned hm_mask; unsigned n_chunks; };

__global__ __launch_bounds__(TPB, 6) void hashenc_kernel(
    const float* __restrict__ x,
    const float2* __restrict__ grid,
    float2* __restrict__ out,
    Cfg cfg)
{
  const unsigned tid = threadIdx.x;
  const unsigned P1 = 2654435761u, P2 = 805459861u;
  const unsigned m = cfg.hm_mask;

  // grid-stride over 256-point chunks; all blocks advance chunk-iters together
  for (unsigned chunk = blockIdx.x; chunk < cfg.n_chunks; chunk += NBLOCKS) {
    const unsigned pt = chunk * TPB + tid;
    const float px = x[pt * 3u + 0u];
    const float py = x[pt * 3u + 1u];
    const float pz = x[pt * 3u + 2u];

    float accx[NLVL], accy[NLVL];

#pragma unroll
    for (int L = 0; L < NLVL; ++L) {               // level-inner: chip-wide level sweep
      const LevelCfg c = cfg.lv[L];                // unrolled const L -> SGPR kernarg loads

      // pos = scale*x + 0.5 ; frac = pos - floor(pos) — contraction-free,
      // matches the reference f32 op chain (validated absmax 4.8e-7).
      const float p0 = __fadd_rn(__fmul_rn(c.scale, px), 0.5f);
      const float p1 = __fadd_rn(__fmul_rn(c.scale, py), 0.5f);
      const float p2 = __fadd_rn(__fmul_rn(c.scale, pz), 0.5f);
      const float fl0 = floorf(p0), fl1 = floorf(p1), fl2 = floorf(p2);
      const float fr0 = __fsub_rn(p0, fl0);
      const float fr1 = __fsub_rn(p1, fl1);
      const float fr2 = __fsub_rn(p2, fl2);
      const unsigned b0 = (unsigned)fl0, b1 = (unsigned)fl1, b2 = (unsigned)fl2;

      // hashed-index building blocks (prime for dim0 is 1)
      const unsigned hx[2] = { b0, b0 + 1u };
      const unsigned hy[2] = { b1 * P1, b1 * P1 + P1 };
      const unsigned hz[2] = { b2 * P2, b2 * P2 + P2 };
      // dense-index building blocks
      const unsigned r = c.res, r2 = r * r;
      const unsigned dbase = b0 + b1 * r + b2 * r2;
      const unsigned dy[2] = { 0u, r };
      const unsigned dz[2] = { 0u, r2 };
      const bool hashed = (c.hashed != 0u);

      const float wxv[2] = { __fsub_rn(1.0f, fr0), fr0 };
      const float wyv[2] = { __fsub_rn(1.0f, fr1), fr1 };
      const float wzv[2] = { __fsub_rn(1.0f, fr2), fr2 };

      unsigned idx[8];
      float w[8];
#pragma unroll
      for (int cc = 0; cc < 8; ++cc) {
        const int bx = (cc >> 2) & 1;              // dim0 (slowest, itertools.product)
        const int by = (cc >> 1) & 1;
        const int bz = cc & 1;                     // dim2 fastest
        const unsigned ih = (hx[bx] ^ hy[by] ^ hz[bz]) & m;
        const unsigned id = dbase + (unsigned)bx + dy[by] + dz[bz];
        idx[cc] = hashed ? ih : id;                // branchless
        w[cc] = __fmul_rn(__fmul_rn(wxv[bx], wyv[by]), wzv[bz]);
      }

      const float2* __restrict__ g = grid + c.offset;
      float ax = 0.0f, ay = 0.0f;
#pragma unroll
      for (int cc = 0; cc < 8; ++cc) {             // 8 independent gathers -> MLP
        const float2 v = g[idx[cc]];
        ax = __fmaf_rn(v.x, w[cc], ax);
        ay = __fmaf_rn(v.y, w[cc], ay);
      }
      accx[L] = ax; accy[L] = ay;                  // static index (unrolled) -> VGPRs
    }

    // one full 128B out-line per thread (16 levels x float2): full-line dirty,
    // no RFO, no write amplification. 128B-aligned.
    float4* o = (float4*)(out + (size_t)pt * 16u);
#pragma unroll
    for (int j = 0; j < 8; ++j)
      o[j] = make_float4(accx[2 * j], accy[2 * j], accx[2 * j + 1], accy[2 * j + 1]);
  }
}

extern "C" void kernel_launch(void* const* d_in, const int* in_sizes, int n_in,
                              void* d_out, int out_size, void* d_ws, size_t ws_size,
                              hipStream_t stream) {
  const float*  x    = (const float*)d_in[0];
  const float2* grid = (const float2*)d_in[1];
  float2*       out  = (float2*)d_out;

  // Mirror reference _level_config() in double precision (same libm chain
  // CPython's math module uses -> bit-identical scales/res/offsets).
  Cfg cfg;
  const unsigned hashmap_size = 1u << 19;
  const double per_level_scale = exp(log(2048.0 * 1.0 / 16.0) / (NLVL - 1));
  const double b = log2(per_level_scale);
  unsigned n_params = 0;
  for (int i = 0; i < NLVL; ++i) {
    const double scale = pow(2.0, (double)i * b) * 16.0 - 1.0;
    const int res = (int)ceil(scale) + 1;
    const double res3 = pow((double)res, 3.0);
    unsigned p = (unsigned)(ceil(res3 / 8.0) * 8.0);
    if (p > hashmap_size) p = hashmap_size;
    cfg.lv[i].hashed = (res3 > (double)p) ? 1u : 0u;
    cfg.lv[i].offset = n_params;
    cfg.lv[i].scale  = (float)scale;
    cfg.lv[i].res    = (unsigned)res;
    n_params += p;
  }
  cfg.hm_mask = hashmap_size - 1u;

  const unsigned n_points = (unsigned)(in_sizes[0] / 3);
  cfg.n_chunks = n_points / TPB;                   // 8192 for N=2^21

  hashenc_kernel<<<NBLOCKS, TPB, 0, stream>>>(x, grid, out, cfg);
}

// Round 4
// 1095.142 us; speedup vs baseline: 2.5948x; 2.5948x over previous
//
#include <hip/hip_runtime.h>
#include <cmath>

#define NLVL 16
#define NDENSE 5     // levels 0..4: dense tables, 2.65 MB total -> computed in K_final
#define NHASH 11     // levels 5..15: hashed, 4 MB table each -> one pass per level
#define TPB 256

struct LevelCfg { float scale; unsigned offset; unsigned res; unsigned hashed; };
struct Cfg { LevelCfg lv[NDENSE]; };

// One hashed level per launch: chip-wide, only this level's 4 MB table is live
// -> table stays L2-resident per XCD. Result staged into d_out chunk-locally:
// chunk c (16 points) owns out2[c*256 .. c*256+255]; slot s=L-5 lives at
// out2[c*256 + s*16 + (pt&15)] -> 128B-aligned full-line segments, coalesced.
__global__ __launch_bounds__(TPB) void khash_kernel(
    const float* __restrict__ x,
    const float2* __restrict__ grid,   // pre-offset to this level's table
    float2* __restrict__ out2,
    float scale, unsigned hm_mask, unsigned slot)
{
  const unsigned pt = blockIdx.x * TPB + threadIdx.x;
  const float px = x[pt * 3u + 0u];
  const float py = x[pt * 3u + 1u];
  const float pz = x[pt * 3u + 2u];

  // contraction-free f32 chain (validated absmax 4.8e-7 in round 2)
  const float p0 = __fadd_rn(__fmul_rn(scale, px), 0.5f);
  const float p1 = __fadd_rn(__fmul_rn(scale, py), 0.5f);
  const float p2 = __fadd_rn(__fmul_rn(scale, pz), 0.5f);
  const float fl0 = floorf(p0), fl1 = floorf(p1), fl2 = floorf(p2);
  const float fr0 = __fsub_rn(p0, fl0);
  const float fr1 = __fsub_rn(p1, fl1);
  const float fr2 = __fsub_rn(p2, fl2);
  const unsigned b0 = (unsigned)fl0, b1 = (unsigned)fl1, b2 = (unsigned)fl2;

  const unsigned P1 = 2654435761u, P2 = 805459861u;
  const unsigned hx[2] = { b0, b0 + 1u };
  const unsigned hy[2] = { b1 * P1, b1 * P1 + P1 };
  const unsigned hz[2] = { b2 * P2, b2 * P2 + P2 };

  const float wxv[2] = { __fsub_rn(1.0f, fr0), fr0 };
  const float wyv[2] = { __fsub_rn(1.0f, fr1), fr1 };
  const float wzv[2] = { __fsub_rn(1.0f, fr2), fr2 };

  unsigned idx[8];
  float w[8];
#pragma unroll
  for (int cc = 0; cc < 8; ++cc) {
    const int bx = (cc >> 2) & 1;      // dim0 slowest (itertools.product order)
    const int by = (cc >> 1) & 1;
    const int bz = cc & 1;             // dim2 fastest
    idx[cc] = (hx[bx] ^ hy[by] ^ hz[bz]) & hm_mask;
    w[cc] = __fmul_rn(__fmul_rn(wxv[bx], wyv[by]), wzv[bz]);
  }

  float ax = 0.0f, ay = 0.0f;
#pragma unroll
  for (int cc = 0; cc < 8; ++cc) {     // 8 independent gathers -> MLP
    const float2 v = grid[idx[cc]];
    ax = __fmaf_rn(v.x, w[cc], ax);
    ay = __fmaf_rn(v.y, w[cc], ay);
  }

  out2[(pt >> 4) * 256u + slot * 16u + (pt & 15u)] = make_float2(ax, ay);
}

// Final pass: round-2 geometry (16 points x 16 levels per block; zero write
// amplification measured). Lanes lvl<5 gather dense tables directly; lanes
// lvl>=5 read the staged value from THIS block's own out-region (no cross-
// block race), then barrier, then overwrite region with final layout.
__global__ __launch_bounds__(TPB) void kfinal_kernel(
    const float* __restrict__ x,
    const float2* __restrict__ grid,
    float2* __restrict__ out2,
    Cfg cfg)
{
  __shared__ float s_x[48];
  __shared__ LevelCfg s_cfg[NDENSE];
  const unsigned tid = threadIdx.x;
  const unsigned pt0 = blockIdx.x * 16u;
  if (tid < NDENSE) s_cfg[tid] = cfg.lv[tid];
  if (tid < 48u)  s_x[tid] = x[pt0 * 3u + tid];
  __syncthreads();

  const unsigned lvl = tid & 15u;
  const unsigned lp  = tid >> 4;

  float ax, ay;
  if (lvl < NDENSE) {
    const LevelCfg c = s_cfg[lvl];
    const float px = s_x[lp * 3 + 0];
    const float py = s_x[lp * 3 + 1];
    const float pz = s_x[lp * 3 + 2];

    const float p0 = __fadd_rn(__fmul_rn(c.scale, px), 0.5f);
    const float p1 = __fadd_rn(__fmul_rn(c.scale, py), 0.5f);
    const float p2 = __fadd_rn(__fmul_rn(c.scale, pz), 0.5f);
    const float fl0 = floorf(p0), fl1 = floorf(p1), fl2 = floorf(p2);
    const float fr0 = __fsub_rn(p0, fl0);
    const float fr1 = __fsub_rn(p1, fl1);
    const float fr2 = __fsub_rn(p2, fl2);
    const unsigned b0 = (unsigned)fl0, b1 = (unsigned)fl1, b2 = (unsigned)fl2;

    const unsigned r = c.res, r2 = r * r;
    const unsigned dbase = b0 + b1 * r + b2 * r2;
    const unsigned dy[2] = { 0u, r };
    const unsigned dz[2] = { 0u, r2 };

    const float wxv[2] = { __fsub_rn(1.0f, fr0), fr0 };
    const float wyv[2] = { __fsub_rn(1.0f, fr1), fr1 };
    const float wzv[2] = { __fsub_rn(1.0f, fr2), fr2 };

    const float2* __restrict__ g = grid + c.offset;
    ax = 0.0f; ay = 0.0f;
#pragma unroll
    for (int cc = 0; cc < 8; ++cc) {
      const int bx = (cc >> 2) & 1;
      const int by = (cc >> 1) & 1;
      const int bz = cc & 1;
      const unsigned id = dbase + (unsigned)bx + dy[by] + dz[bz];
      const float wv = __fmul_rn(__fmul_rn(wxv[bx], wyv[by]), wzv[bz]);
      const float2 v = g[id];
      ax = __fmaf_rn(v.x, wv, ax);
      ay = __fmaf_rn(v.y, wv, ay);
    }
  } else {
    const float2 v = out2[blockIdx.x * 256u + (lvl - NDENSE) * 16u + lp];
    ax = v.x; ay = v.y;
  }

  __syncthreads();   // all staged reads done before region is overwritten
  out2[blockIdx.x * 256u + tid] = make_float2(ax, ay);  // = out[pt0+lp][lvl]
}

extern "C" void kernel_launch(void* const* d_in, const int* in_sizes, int n_in,
                              void* d_out, int out_size, void* d_ws, size_t ws_size,
                              hipStream_t stream) {
  const float*  x    = (const float*)d_in[0];
  const float2* grid = (const float2*)d_in[1];
  float2*       out2 = (float2*)d_out;

  // Mirror reference _level_config() in double (same libm chain as CPython).
  const unsigned hashmap_size = 1u << 19;
  const double per_level_scale = exp(log(2048.0 * 1.0 / 16.0) / (NLVL - 1));
  const double b = log2(per_level_scale);
  float  scales[NLVL];
  unsigned offsets[NLVL], ress[NLVL], hashedv[NLVL];
  unsigned n_params = 0;
  for (int i = 0; i < NLVL; ++i) {
    const double scale = pow(2.0, (double)i * b) * 16.0 - 1.0;
    const int res = (int)ceil(scale) + 1;
    const double res3 = pow((double)res, 3.0);
    unsigned p = (unsigned)(ceil(res3 / 8.0) * 8.0);
    if (p > hashmap_size) p = hashmap_size;
    hashedv[i] = (res3 > (double)p) ? 1u : 0u;
    offsets[i] = n_params;
    scales[i]  = (float)scale;
    ress[i]    = (unsigned)res;
    n_params += p;
  }

  const unsigned n_points = (unsigned)(in_sizes[0] / 3);
  const unsigned nblk = n_points / TPB;            // 8192 for N=2^21

  // 11 hashed passes, stream-serialized: one 4MB table L2-resident at a time.
  for (int L = NDENSE; L < NLVL; ++L) {
    khash_kernel<<<nblk, TPB, 0, stream>>>(
        x, grid + offsets[L], out2, scales[L], hashmap_size - 1u,
        (unsigned)(L - NDENSE));
  }

  // Final pass: dense levels + assemble.
  Cfg cfg;
  for (int i = 0; i < NDENSE; ++i) {
    cfg.lv[i].scale  = scales[i];
    cfg.lv[i].offset = offsets[i];
    cfg.lv[i].res    = ress[i];
    cfg.lv[i].hashed = hashedv[i];
  }
  kfinal_kernel<<<n_points / 16u, TPB, 0, stream>>>(x, grid, out2, cfg);
}

// Round 5
// 939.490 us; speedup vs baseline: 3.0247x; 1.1657x over previous
//
#include <hip/hip_runtime.h>
#include <cmath>

#define NLVL 16
#define NDENSE 5     // levels 0..4 dense (2.65 MB total) -> fused kdense pass
#define TPB 256

struct LevelCfg { float scale; unsigned offset; unsigned res; };
struct DCfg { LevelCfg lv[NDENSE]; };

// One hashed level per launch (keeps its 4MB table L2-resident chip-wide).
// Corner pairing: dim0 prime is 1, so b0 even -> idx(bx=1)=idx(bx=0)^1 ->
// one aligned float4 load covers both corners (halves L2 requests for 50% of
// points). Staged chunk-locally into d_out: slot s=L-5 of chunk c at
// out2[c*256 + s*16 + (pt&15)] (128B-aligned coalesced segments).
__global__ __launch_bounds__(TPB) void khash_kernel(
    const float* __restrict__ x,
    const float2* __restrict__ grid,   // pre-offset to this level's table
    float2* __restrict__ out2,
    float scale, unsigned hm_mask, unsigned slot)
{
  const unsigned pt = blockIdx.x * TPB + threadIdx.x;
  const float px = x[pt * 3u + 0u];
  const float py = x[pt * 3u + 1u];
  const float pz = x[pt * 3u + 2u];

  // contraction-free f32 chain — must match reference rounding exactly
  const float p0 = __fadd_rn(__fmul_rn(scale, px), 0.5f);
  const float p1 = __fadd_rn(__fmul_rn(scale, py), 0.5f);
  const float p2 = __fadd_rn(__fmul_rn(scale, pz), 0.5f);
  const float fl0 = floorf(p0), fl1 = floorf(p1), fl2 = floorf(p2);
  const float fr0 = __fsub_rn(p0, fl0);
  const float fr1 = __fsub_rn(p1, fl1);
  const float fr2 = __fsub_rn(p2, fl2);
  const unsigned b0 = (unsigned)fl0, b1 = (unsigned)fl1, b2 = (unsigned)fl2;

  const unsigned P1 = 2654435761u, P2 = 805459861u;
  const unsigned hy0 = b1 * P1, hy1 = hy0 + P1;
  const unsigned hz0 = b2 * P2, hz1 = hz0 + P2;
  // j = (by<<1)|bz
  const unsigned rest[4] = { hy0 ^ hz0, hy0 ^ hz1, hy1 ^ hz0, hy1 ^ hz1 };

  float2 v0[4], v1[4];   // bx=0 / bx=1 corner values per j
  if ((b0 & 1u) == 0u) {
    // b0 even: idx1 = idx0 ^ 1 -> aligned pair -> 4 float4 loads (4 requests)
    const float4* __restrict__ g4 = (const float4*)grid;
#pragma unroll
    for (int j = 0; j < 4; ++j) {
      const unsigned i0 = (b0 ^ rest[j]) & hm_mask;
      const float4 q = g4[i0 >> 1];
      const float2 lo = make_float2(q.x, q.y);
      const float2 hi = make_float2(q.z, q.w);
      const bool odd = (i0 & 1u) != 0u;
      v0[j] = odd ? hi : lo;
      v1[j] = odd ? lo : hi;
    }
  } else {
    // b0 odd: unrelated indices -> 8 float2 loads
#pragma unroll
    for (int j = 0; j < 4; ++j) {
      const unsigned i0 = (b0 ^ rest[j]) & hm_mask;
      const unsigned i1 = ((b0 + 1u) ^ rest[j]) & hm_mask;
      v0[j] = grid[i0];
      v1[j] = grid[i1];
    }
  }

  const float wxv[2] = { __fsub_rn(1.0f, fr0), fr0 };
  const float wyv[2] = { __fsub_rn(1.0f, fr1), fr1 };
  const float wzv[2] = { __fsub_rn(1.0f, fr2), fr2 };

  // accumulate in reference corner order cc=(bx<<2)|(by<<1)|bz
  float ax = 0.0f, ay = 0.0f;
#pragma unroll
  for (int j = 0; j < 4; ++j) {
    const float w = __fmul_rn(__fmul_rn(wxv[0], wyv[j >> 1]), wzv[j & 1]);
    ax = __fmaf_rn(v0[j].x, w, ax);
    ay = __fmaf_rn(v0[j].y, w, ay);
  }
#pragma unroll
  for (int j = 0; j < 4; ++j) {
    const float w = __fmul_rn(__fmul_rn(wxv[1], wyv[j >> 1]), wzv[j & 1]);
    ax = __fmaf_rn(v1[j].x, w, ax);
    ay = __fmaf_rn(v1[j].y, w, ay);
  }

  out2[(pt >> 4) * 256u + slot * 16u + (pt & 15u)] = make_float2(ax, ay);
}

// Fused final pass: one thread per point (all 64 lanes active). Computes the
// 5 dense levels (dim0-stride is 1 -> even pairs load as one float4), reads
// its chunk's 11 staged hashed values, then overwrites the chunk region with
// the final [pt][lvl] layout. Each 16-point chunk is owned by exactly one
// wave (64 thr = 4 chunks), and an explicit vmcnt(0) orders all staged reads
// before the overwriting stores.
__global__ __launch_bounds__(TPB) void kdense_kernel(
    const float* __restrict__ x,
    const float2* __restrict__ grid,
    float2* out2,                      // NOT restrict: read + write alias
    DCfg cfg)
{
  const unsigned pt = blockIdx.x * TPB + threadIdx.x;
  const unsigned chunk = pt >> 4, lp = pt & 15u;
  const float px = x[pt * 3u + 0u];
  const float py = x[pt * 3u + 1u];
  const float pz = x[pt * 3u + 2u];

  float2 fv[NLVL];

  // staged hashed results (this thread's own 11 values), issued early
#pragma unroll
  for (int s = 0; s < NLVL - NDENSE; ++s)
    fv[NDENSE + s] = out2[chunk * 256u + (unsigned)s * 16u + lp];

#pragma unroll
  for (int L = 0; L < NDENSE; ++L) {
    const LevelCfg c = cfg.lv[L];
    const float p0 = __fadd_rn(__fmul_rn(c.scale, px), 0.5f);
    const float p1 = __fadd_rn(__fmul_rn(c.scale, py), 0.5f);
    const float p2 = __fadd_rn(__fmul_rn(c.scale, pz), 0.5f);
    const float fl0 = floorf(p0), fl1 = floorf(p1), fl2 = floorf(p2);
    const float fr0 = __fsub_rn(p0, fl0);
    const float fr1 = __fsub_rn(p1, fl1);
    const float fr2 = __fsub_rn(p2, fl2);
    const unsigned b0 = (unsigned)fl0, b1 = (unsigned)fl1, b2 = (unsigned)fl2;

    const unsigned r = c.res, r2 = r * r;
    // fold table offset in (multiple of 8 entries -> parity & 16B alignment kept)
    const unsigned dbase = b0 + b1 * r + b2 * r2 + c.offset;
    const unsigned doff[4] = { 0u, r2, r, r + r2 };   // j=(by<<1)|bz

    float2 v0[4], v1[4];
#pragma unroll
    for (int j = 0; j < 4; ++j) {
      const unsigned i0 = dbase + doff[j];            // bx=0 ; bx=1 is i0+1
      if ((i0 & 1u) == 0u) {
        const float4 q = *(const float4*)(grid + i0); // 16B-aligned pair load
        v0[j] = make_float2(q.x, q.y);
        v1[j] = make_float2(q.z, q.w);
      } else {
        v0[j] = grid[i0];
        v1[j] = grid[i0 + 1u];
      }
    }

    const float wxv[2] = { __fsub_rn(1.0f, fr0), fr0 };
    const float wyv[2] = { __fsub_rn(1.0f, fr1), fr1 };
    const float wzv[2] = { __fsub_rn(1.0f, fr2), fr2 };

    float ax = 0.0f, ay = 0.0f;
#pragma unroll
    for (int j = 0; j < 4; ++j) {
      const float w = __fmul_rn(__fmul_rn(wxv[0], wyv[j >> 1]), wzv[j & 1]);
      ax = __fmaf_rn(v0[j].x, w, ax);
      ay = __fmaf_rn(v0[j].y, w, ay);
    }
#pragma unroll
    for (int j = 0; j < 4; ++j) {
      const float w = __fmul_rn(__fmul_rn(wxv[1], wyv[j >> 1]), wzv[j & 1]);
      ax = __fmaf_rn(v1[j].x, w, ax);
      ay = __fmaf_rn(v1[j].y, w, ay);
    }
    fv[L] = make_float2(ax, ay);
  }

  // all staged loads must complete before the region is overwritten
  asm volatile("s_waitcnt vmcnt(0)" ::: "memory");

  float4* o = (float4*)(out2 + (size_t)pt * 16u);     // 128B-aligned line
#pragma unroll
  for (int j = 0; j < 8; ++j)
    o[j] = make_float4(fv[2 * j].x, fv[2 * j].y, fv[2 * j + 1].x, fv[2 * j + 1].y);
}

extern "C" void kernel_launch(void* const* d_in, const int* in_sizes, int n_in,
                              void* d_out, int out_size, void* d_ws, size_t ws_size,
                              hipStream_t stream) {
  const float*  x    = (const float*)d_in[0];
  const float2* grid = (const float2*)d_in[1];
  float2*       out2 = (float2*)d_out;

  // Mirror reference _level_config() in double (same libm chain as CPython).
  const unsigned hashmap_size = 1u << 19;
  const double per_level_scale = exp(log(2048.0 * 1.0 / 16.0) / (NLVL - 1));
  const double b = log2(per_level_scale);
  float  scales[NLVL];
  unsigned offsets[NLVL], ress[NLVL];
  unsigned n_params = 0;
  for (int i = 0; i < NLVL; ++i) {
    const double scale = pow(2.0, (double)i * b) * 16.0 - 1.0;
    const int res = (int)ceil(scale) + 1;
    const double res3 = pow((double)res, 3.0);
    unsigned p = (unsigned)(ceil(res3 / 8.0) * 8.0);
    if (p > hashmap_size) p = hashmap_size;
    offsets[i] = n_params;
    scales[i]  = (float)scale;
    ress[i]    = (unsigned)res;
    n_params += p;
  }

  const unsigned n_points = (unsigned)(in_sizes[0] / 3);
  const unsigned nblk = n_points / TPB;

  // 11 hashed passes, stream-serialized: one 4MB table L2-resident at a time.
  for (int L = NDENSE; L < NLVL; ++L) {
    khash_kernel<<<nblk, TPB, 0, stream>>>(
        x, grid + offsets[L], out2, scales[L], hashmap_size - 1u,
        (unsigned)(L - NDENSE));
  }

  DCfg cfg;
  for (int i = 0; i < NDENSE; ++i) {
    cfg.lv[i].scale  = scales[i];
    cfg.lv[i].offset = offsets[i];
    cfg.lv[i].res    = ress[i];
  }
  kdense_kernel<<<nblk, TPB, 0, stream>>>(x, grid, out2, cfg);
}

// Round 6
// 837.692 us; speedup vs baseline: 3.3922x; 1.1215x over previous
//
#include <hip/hip_runtime.h>
#include <cmath>

#define NLVL 16
#define NDENSE 5     // levels 0..4 dense (2.65 MB total) -> fused in final pass
#define TPB 256
#define NP 2         // points per khash thread (MLP: ~12 gathers in flight/lane)

struct LevelCfg { float scale; unsigned offset; unsigned res; };
struct DCfg { LevelCfg lv[NDENSE]; };

// One hashed level per launch (4MB table stays L2-resident chip-wide).
// 2 points per thread: all ~12 paired gather loads issued before any FMA.
// Staged chunk-locally into d_out: slot s=L-5 of chunk c at
// out2[c*256 + s*16 + (pt&15)] (128B-aligned coalesced segments).
__global__ __launch_bounds__(TPB) void khash_kernel(
    const float* __restrict__ x,
    const float2* __restrict__ grid,   // pre-offset to this level's table
    float2* __restrict__ out2,
    float scale, unsigned hm_mask, unsigned slot)
{
  const unsigned P1 = 2654435761u, P2 = 805459861u;
  const unsigned base = blockIdx.x * (TPB * NP) + threadIdx.x;

  unsigned pts[NP], b0v[NP];
  unsigned restv[NP][4];
  float wx[NP][2], wy[NP][2], wz[NP][2];
  float4 q[NP][4];          // even-b0 path: aligned pair loads
  float2 oa[NP][4], ob[NP][4]; // odd-b0 path: two float2 loads

#pragma unroll
  for (int p = 0; p < NP; ++p) {
    const unsigned pt = base + (unsigned)p * TPB;
    pts[p] = pt;
    const float px = x[pt * 3u + 0u];
    const float py = x[pt * 3u + 1u];
    const float pz = x[pt * 3u + 2u];

    // contraction-free f32 chain — matches reference rounding exactly
    const float p0 = __fadd_rn(__fmul_rn(scale, px), 0.5f);
    const float p1 = __fadd_rn(__fmul_rn(scale, py), 0.5f);
    const float p2 = __fadd_rn(__fmul_rn(scale, pz), 0.5f);
    const float fl0 = floorf(p0), fl1 = floorf(p1), fl2 = floorf(p2);
    const float fr0 = __fsub_rn(p0, fl0);
    const float fr1 = __fsub_rn(p1, fl1);
    const float fr2 = __fsub_rn(p2, fl2);
    const unsigned b0 = (unsigned)fl0, b1 = (unsigned)fl1, b2 = (unsigned)fl2;
    b0v[p] = b0;

    const unsigned hy0 = b1 * P1, hy1 = hy0 + P1;
    const unsigned hz0 = b2 * P2, hz1 = hz0 + P2;
    restv[p][0] = hy0 ^ hz0; restv[p][1] = hy0 ^ hz1;   // j=(by<<1)|bz
    restv[p][2] = hy1 ^ hz0; restv[p][3] = hy1 ^ hz1;

    wx[p][0] = __fsub_rn(1.0f, fr0); wx[p][1] = fr0;
    wy[p][0] = __fsub_rn(1.0f, fr1); wy[p][1] = fr1;
    wz[p][0] = __fsub_rn(1.0f, fr2); wz[p][1] = fr2;
  }

  // issue ALL gather loads (both points) before consuming any
#pragma unroll
  for (int p = 0; p < NP; ++p) {
    const unsigned b0 = b0v[p];
    if ((b0 & 1u) == 0u) {
      const float4* __restrict__ g4 = (const float4*)grid;
#pragma unroll
      for (int j = 0; j < 4; ++j) {
        const unsigned i0 = (b0 ^ restv[p][j]) & hm_mask;
        q[p][j] = g4[i0 >> 1];
      }
    }
    if ((b0v[p] & 1u) != 0u) {
#pragma unroll
      for (int j = 0; j < 4; ++j) {
        const unsigned i0 = (b0v[p] ^ restv[p][j]) & hm_mask;
        const unsigned i1 = ((b0v[p] + 1u) ^ restv[p][j]) & hm_mask;
        oa[p][j] = grid[i0];
        ob[p][j] = grid[i1];
      }
    }
  }

#pragma unroll
  for (int p = 0; p < NP; ++p) {
    const unsigned b0 = b0v[p];
    const bool beven = (b0 & 1u) == 0u;
    float ax = 0.0f, ay = 0.0f;
#pragma unroll
    for (int j = 0; j < 4; ++j) {
      const unsigned i0 = (b0 ^ restv[p][j]) & hm_mask;
      const bool odd = (i0 & 1u) != 0u;
      // v0 = corner bx=0, v1 = corner bx=1 (order via i0 parity on even path)
      const float2 qlo = make_float2(q[p][j].x, q[p][j].y);
      const float2 qhi = make_float2(q[p][j].z, q[p][j].w);
      const float2 v0 = beven ? (odd ? qhi : qlo) : oa[p][j];
      const float2 v1 = beven ? (odd ? qlo : qhi) : ob[p][j];
      const float w0 = __fmul_rn(__fmul_rn(wx[p][0], wy[p][j >> 1]), wz[p][j & 1]);
      const float w1 = __fmul_rn(__fmul_rn(wx[p][1], wy[p][j >> 1]), wz[p][j & 1]);
      ax = __fmaf_rn(v0.x, w0, ax);  ay = __fmaf_rn(v0.y, w0, ay);
      ax = __fmaf_rn(v1.x, w1, ax);  ay = __fmaf_rn(v1.y, w1, ay);
    }
    const unsigned pt = pts[p];
    out2[(pt >> 4) * 256u + slot * 16u + (pt & 15u)] = make_float2(ax, ay);
  }
}

// Final pass, 16 lanes per point (proven latency-hiding shape): lane lvl<5
// computes dense level lvl with corner pairing; lane lvl>=5 reads its staged
// value (issued at kernel top). Barrier, then one coalesced 8B store/thread.
__global__ __launch_bounds__(TPB) void kfinal_kernel(
    const float* __restrict__ x,
    const float2* __restrict__ grid,
    float2* out2,                      // read + write alias (chunk-local)
    DCfg cfg)
{
  __shared__ float s_x[48];
  __shared__ LevelCfg s_cfg[NDENSE];
  const unsigned tid = threadIdx.x;
  const unsigned lvl = tid & 15u;
  const unsigned lp  = tid >> 4;
  const unsigned pt0 = blockIdx.x * 16u;

  // staged hashed result: issue FIRST (overlaps entire dense computation)
  float2 staged = make_float2(0.0f, 0.0f);
  if (lvl >= NDENSE)
    staged = out2[blockIdx.x * 256u + (lvl - NDENSE) * 16u + lp];

  if (tid < NDENSE) s_cfg[tid] = cfg.lv[tid];
  if (tid < 48u)  s_x[tid] = x[pt0 * 3u + tid];
  __syncthreads();

  float ax, ay;
  if (lvl < NDENSE) {
    const LevelCfg c = s_cfg[lvl];
    const float px = s_x[lp * 3 + 0];
    const float py = s_x[lp * 3 + 1];
    const float pz = s_x[lp * 3 + 2];

    const float p0 = __fadd_rn(__fmul_rn(c.scale, px), 0.5f);
    const float p1 = __fadd_rn(__fmul_rn(c.scale, py), 0.5f);
    const float p2 = __fadd_rn(__fmul_rn(c.scale, pz), 0.5f);
    const float fl0 = floorf(p0), fl1 = floorf(p1), fl2 = floorf(p2);
    const float fr0 = __fsub_rn(p0, fl0);
    const float fr1 = __fsub_rn(p1, fl1);
    const float fr2 = __fsub_rn(p2, fl2);
    const unsigned b0 = (unsigned)fl0, b1 = (unsigned)fl1, b2 = (unsigned)fl2;

    const unsigned r = c.res, r2 = r * r;
    const unsigned dbase = b0 + b1 * r + b2 * r2 + c.offset; // offset mult. of 8
    const unsigned doff[4] = { 0u, r2, r, r + r2 };          // j=(by<<1)|bz

    // issue all corner loads (paired where 16B-aligned) before any FMA
    unsigned i0[4];
#pragma unroll
    for (int j = 0; j < 4; ++j) i0[j] = dbase + doff[j];
    float4 q[4]; float2 ea[4], eb[4];
#pragma unroll
    for (int j = 0; j < 4; ++j)
      if ((i0[j] & 1u) == 0u) q[j] = *(const float4*)(grid + i0[j]);
#pragma unroll
    for (int j = 0; j < 4; ++j)
      if ((i0[j] & 1u) != 0u) { ea[j] = grid[i0[j]]; eb[j] = grid[i0[j] + 1u]; }

    const float wxv[2] = { __fsub_rn(1.0f, fr0), fr0 };
    const float wyv[2] = { __fsub_rn(1.0f, fr1), fr1 };
    const float wzv[2] = { __fsub_rn(1.0f, fr2), fr2 };

    ax = 0.0f; ay = 0.0f;
#pragma unroll
    for (int j = 0; j < 4; ++j) {
      const bool odd = (i0[j] & 1u) != 0u;
      const float2 v0 = odd ? ea[j] : make_float2(q[j].x, q[j].y);
      const float2 v1 = odd ? eb[j] : make_float2(q[j].z, q[j].w);
      const float w0 = __fmul_rn(__fmul_rn(wxv[0], wyv[j >> 1]), wzv[j & 1]);
      const float w1 = __fmul_rn(__fmul_rn(wxv[1], wyv[j >> 1]), wzv[j & 1]);
      ax = __fmaf_rn(v0.x, w0, ax);  ay = __fmaf_rn(v0.y, w0, ay);
      ax = __fmaf_rn(v1.x, w1, ax);  ay = __fmaf_rn(v1.y, w1, ay);
    }
  } else {
    ax = staged.x; ay = staged.y;
  }

  __syncthreads();   // all staged reads complete before region overwrite
  out2[blockIdx.x * 256u + tid] = make_float2(ax, ay);  // = out[pt0+lp][lvl]
}

extern "C" void kernel_launch(void* const* d_in, const int* in_sizes, int n_in,
                              void* d_out, int out_size, void* d_ws, size_t ws_size,
                              hipStream_t stream) {
  const float*  x    = (const float*)d_in[0];
  const float2* grid = (const float2*)d_in[1];
  float2*       out2 = (float2*)d_out;

  // Mirror reference _level_config() in double (same libm chain as CPython).
  const unsigned hashmap_size = 1u << 19;
  const double per_level_scale = exp(log(2048.0 * 1.0 / 16.0) / (NLVL - 1));
  const double b = log2(per_level_scale);
  float  scales[NLVL];
  unsigned offsets[NLVL], ress[NLVL];
  unsigned n_params = 0;
  for (int i = 0; i < NLVL; ++i) {
    const double scale = pow(2.0, (double)i * b) * 16.0 - 1.0;
    const int res = (int)ceil(scale) + 1;
    const double res3 = pow((double)res, 3.0);
    unsigned p = (unsigned)(ceil(res3 / 8.0) * 8.0);
    if (p > hashmap_size) p = hashmap_size;
    offsets[i] = n_params;
    scales[i]  = (float)scale;
    ress[i]    = (unsigned)res;
    n_params += p;
  }

  const unsigned n_points = (unsigned)(in_sizes[0] / 3);

  // 11 hashed passes, stream-serialized: one 4MB table L2-resident at a time.
  const unsigned nblk_h = n_points / (TPB * NP);
  for (int L = NDENSE; L < NLVL; ++L) {
    khash_kernel<<<nblk_h, TPB, 0, stream>>>(
        x, grid + offsets[L], out2, scales[L], hashmap_size - 1u,
        (unsigned)(L - NDENSE));
  }

  DCfg cfg;
  for (int i = 0; i < NDENSE; ++i) {
    cfg.lv[i].scale  = scales[i];
    cfg.lv[i].offset = offsets[i];
    cfg.lv[i].res    = ress[i];
  }
  kfinal_kernel<<<n_points / 16u, TPB, 0, stream>>>(x, grid, out2, cfg);
}

// Round 7
// 766.755 us; speedup vs baseline: 3.7061x; 1.0925x over previous
//
#include <hip/hip_runtime.h>
#include <cmath>

#define NLVL 16
#define NDENSE 5     // levels 0..4 dense (2.65 MB total) -> fused in final pass
#define TPB 256
#define NP 2         // points per khash thread

struct LevelCfg { float scale; unsigned offset; unsigned res; };
struct DCfg { LevelCfg lv[NDENSE]; };

// One hashed level per launch (4MB table stays L2-resident chip-wide).
// 2 points per thread: all paired gather loads issued before any FMA.
// Staged chunk-locally into d_out: slot s=L-5 of chunk c at
// out2[c*256 + s*16 + (pt&15)] (128B-aligned coalesced segments).
__global__ __launch_bounds__(TPB) void khash_kernel(
    const float* __restrict__ x,
    const float2* __restrict__ grid,   // pre-offset to this level's table
    float2* __restrict__ out2,
    float scale, unsigned hm_mask, unsigned slot)
{
  const unsigned P1 = 2654435761u, P2 = 805459861u;
  const unsigned base = blockIdx.x * (TPB * NP) + threadIdx.x;

  unsigned pts[NP], b0v[NP];
  unsigned restv[NP][4];
  float wx[NP][2], wy[NP][2], wz[NP][2];
  float4 q[NP][4];             // even-b0 path: aligned pair loads
  float2 oa[NP][4], ob[NP][4]; // odd-b0 path: two float2 loads

#pragma unroll
  for (int p = 0; p < NP; ++p) {
    const unsigned pt = base + (unsigned)p * TPB;
    pts[p] = pt;
    const float px = x[pt * 3u + 0u];
    const float py = x[pt * 3u + 1u];
    const float pz = x[pt * 3u + 2u];

    // contraction-free f32 chain — matches reference rounding exactly
    const float p0 = __fadd_rn(__fmul_rn(scale, px), 0.5f);
    const float p1 = __fadd_rn(__fmul_rn(scale, py), 0.5f);
    const float p2 = __fadd_rn(__fmul_rn(scale, pz), 0.5f);
    const float fl0 = floorf(p0), fl1 = floorf(p1), fl2 = floorf(p2);
    const float fr0 = __fsub_rn(p0, fl0);
    const float fr1 = __fsub_rn(p1, fl1);
    const float fr2 = __fsub_rn(p2, fl2);
    const unsigned b0 = (unsigned)fl0, b1 = (unsigned)fl1, b2 = (unsigned)fl2;
    b0v[p] = b0;

    const unsigned hy0 = b1 * P1, hy1 = hy0 + P1;
    const unsigned hz0 = b2 * P2, hz1 = hz0 + P2;
    restv[p][0] = hy0 ^ hz0; restv[p][1] = hy0 ^ hz1;   // j=(by<<1)|bz
    restv[p][2] = hy1 ^ hz0; restv[p][3] = hy1 ^ hz1;

    wx[p][0] = __fsub_rn(1.0f, fr0); wx[p][1] = fr0;
    wy[p][0] = __fsub_rn(1.0f, fr1); wy[p][1] = fr1;
    wz[p][0] = __fsub_rn(1.0f, fr2); wz[p][1] = fr2;
  }

  // issue ALL gather loads (both points) before consuming any
#pragma unroll
  for (int p = 0; p < NP; ++p) {
    const unsigned b0 = b0v[p];
    if ((b0 & 1u) == 0u) {
      const float4* __restrict__ g4 = (const float4*)grid;
#pragma unroll
      for (int j = 0; j < 4; ++j) {
        const unsigned i0 = (b0 ^ restv[p][j]) & hm_mask;
        q[p][j] = g4[i0 >> 1];
      }
    }
    if ((b0v[p] & 1u) != 0u) {
#pragma unroll
      for (int j = 0; j < 4; ++j) {
        const unsigned i0 = (b0v[p] ^ restv[p][j]) & hm_mask;
        const unsigned i1 = ((b0v[p] + 1u) ^ restv[p][j]) & hm_mask;
        oa[p][j] = grid[i0];
        ob[p][j] = grid[i1];
      }
    }
  }

#pragma unroll
  for (int p = 0; p < NP; ++p) {
    const unsigned b0 = b0v[p];
    const bool beven = (b0 & 1u) == 0u;
    float ax = 0.0f, ay = 0.0f;
#pragma unroll
    for (int j = 0; j < 4; ++j) {
      const unsigned i0 = (b0 ^ restv[p][j]) & hm_mask;
      const bool odd = (i0 & 1u) != 0u;
      const float2 qlo = make_float2(q[p][j].x, q[p][j].y);
      const float2 qhi = make_float2(q[p][j].z, q[p][j].w);
      const float2 v0 = beven ? (odd ? qhi : qlo) : oa[p][j];
      const float2 v1 = beven ? (odd ? qlo : qhi) : ob[p][j];
      const float w0 = __fmul_rn(__fmul_rn(wx[p][0], wy[p][j >> 1]), wz[p][j & 1]);
      const float w1 = __fmul_rn(__fmul_rn(wx[p][1], wy[p][j >> 1]), wz[p][j & 1]);
      ax = __fmaf_rn(v0.x, w0, ax);  ay = __fmaf_rn(v0.y, w0, ay);
      ax = __fmaf_rn(v1.x, w1, ax);  ay = __fmaf_rn(v1.y, w1, ay);
    }
    const unsigned pt = pts[p];
    out2[(pt >> 4) * 256u + slot * 16u + (pt & 15u)] = make_float2(ax, ay);
  }
}

// Final pass, 16 lanes per point, 2 points per thread (2 chunks per block).
// Dense corner-pair (i0,i0+1) is ALWAYS contiguous (dim0-stride 1), so load
// it as ONE unaligned 16B load (gfx950 supports unaligned dwordx4): 4
// requests per (point,level) with zero parity branching. Staged hashed reads
// issued at kernel top. __syncthreads() (drains vmcnt) orders staged reads
// before the overwriting final stores; both chunks owned by this block only.
__global__ __launch_bounds__(TPB) void kfinal_kernel(
    const float* __restrict__ x,
    const float2* __restrict__ grid,
    float2* out2,                      // read + write alias (chunk-local)
    DCfg cfg)
{
  __shared__ float s_x[96];
  __shared__ LevelCfg s_cfg[NDENSE];
  const unsigned tid = threadIdx.x;
  const unsigned lvl = tid & 15u;
  const unsigned lp  = tid >> 4;
  const unsigned chunk0 = blockIdx.x * 2u;
  const unsigned pt0 = chunk0 * 16u;   // first of this block's 32 points

  // staged hashed results: issue FIRST (overlap entire dense computation)
  float2 staged0 = make_float2(0.0f, 0.0f), staged1 = staged0;
  if (lvl >= NDENSE) {
    staged0 = out2[chunk0 * 256u + (lvl - NDENSE) * 16u + lp];
    staged1 = out2[(chunk0 + 1u) * 256u + (lvl - NDENSE) * 16u + lp];
  }

  if (tid < NDENSE) s_cfg[tid] = cfg.lv[tid];
  if (tid < 96u) s_x[tid] = x[pt0 * 3u + tid];
  __syncthreads();

  float ax[2], ay[2];
  if (lvl < NDENSE) {
    const LevelCfg c = s_cfg[lvl];
    const unsigned r = c.res, r2 = r * r;
    const unsigned doff[4] = { 0u, r2, r, r + r2 };  // j=(by<<1)|bz

    unsigned i0[2][4];
    float wxv[2][2], wyv[2][2], wzv[2][2];
#pragma unroll
    for (int p = 0; p < 2; ++p) {
      const unsigned lpp = (unsigned)p * 16u + lp;
      const float px = s_x[lpp * 3u + 0u];
      const float py = s_x[lpp * 3u + 1u];
      const float pz = s_x[lpp * 3u + 2u];
      const float p0 = __fadd_rn(__fmul_rn(c.scale, px), 0.5f);
      const float p1 = __fadd_rn(__fmul_rn(c.scale, py), 0.5f);
      const float p2 = __fadd_rn(__fmul_rn(c.scale, pz), 0.5f);
      const float fl0 = floorf(p0), fl1 = floorf(p1), fl2 = floorf(p2);
      const float fr0 = __fsub_rn(p0, fl0);
      const float fr1 = __fsub_rn(p1, fl1);
      const float fr2 = __fsub_rn(p2, fl2);
      const unsigned b0 = (unsigned)fl0, b1 = (unsigned)fl1, b2 = (unsigned)fl2;
      const unsigned dbase = b0 + b1 * r + b2 * r2 + c.offset;
#pragma unroll
      for (int j = 0; j < 4; ++j) i0[p][j] = dbase + doff[j];
      wxv[p][0] = __fsub_rn(1.0f, fr0); wxv[p][1] = fr0;
      wyv[p][0] = __fsub_rn(1.0f, fr1); wyv[p][1] = fr1;
      wzv[p][0] = __fsub_rn(1.0f, fr2); wzv[p][1] = fr2;
    }

    // issue all 8 pair-loads (one 16B load per corner pair) before any FMA
    float q[2][4][4];
#pragma unroll
    for (int p = 0; p < 2; ++p)
#pragma unroll
      for (int j = 0; j < 4; ++j)
        __builtin_memcpy(&q[p][j][0], grid + i0[p][j], 16);  // 8B-aligned 16B load

#pragma unroll
    for (int p = 0; p < 2; ++p) {
      float axx = 0.0f, ayy = 0.0f;
#pragma unroll
      for (int j = 0; j < 4; ++j) {
        const float w0 = __fmul_rn(__fmul_rn(wxv[p][0], wyv[p][j >> 1]), wzv[p][j & 1]);
        const float w1 = __fmul_rn(__fmul_rn(wxv[p][1], wyv[p][j >> 1]), wzv[p][j & 1]);
        axx = __fmaf_rn(q[p][j][0], w0, axx);  ayy = __fmaf_rn(q[p][j][1], w0, ayy);
        axx = __fmaf_rn(q[p][j][2], w1, axx);  ayy = __fmaf_rn(q[p][j][3], w1, ayy);
      }
      ax[p] = axx; ay[p] = ayy;
    }
  } else {
    ax[0] = staged0.x; ay[0] = staged0.y;
    ax[1] = staged1.x; ay[1] = staged1.y;
  }

  __syncthreads();   // all staged reads complete before region overwrite
  out2[chunk0 * 256u + tid]        = make_float2(ax[0], ay[0]);
  out2[(chunk0 + 1u) * 256u + tid] = make_float2(ax[1], ay[1]);
}

extern "C" void kernel_launch(void* const* d_in, const int* in_sizes, int n_in,
                              void* d_out, int out_size, void* d_ws, size_t ws_size,
                              hipStream_t stream) {
  const float*  x    = (const float*)d_in[0];
  const float2* grid = (const float2*)d_in[1];
  float2*       out2 = (float2*)d_out;

  // Mirror reference _level_config() in double (same libm chain as CPython).
  const unsigned hashmap_size = 1u << 19;
  const double per_level_scale = exp(log(2048.0 * 1.0 / 16.0) / (NLVL - 1));
  const double b = log2(per_level_scale);
  float  scales[NLVL];
  unsigned offsets[NLVL], ress[NLVL];
  unsigned n_params = 0;
  for (int i = 0; i < NLVL; ++i) {
    const double scale = pow(2.0, (double)i * b) * 16.0 - 1.0;
    const int res = (int)ceil(scale) + 1;
    const double res3 = pow((double)res, 3.0);
    unsigned p = (unsigned)(ceil(res3 / 8.0) * 8.0);
    if (p > hashmap_size) p = hashmap_size;
    offsets[i] = n_params;
    scales[i]  = (float)scale;
    ress[i]    = (unsigned)res;
    n_params += p;
  }

  const unsigned n_points = (unsigned)(in_sizes[0] / 3);

  // 11 hashed passes, stream-serialized: one 4MB table L2-resident at a time.
  const unsigned nblk_h = n_points / (TPB * NP);
  for (int L = NDENSE; L < NLVL; ++L) {
    khash_kernel<<<nblk_h, TPB, 0, stream>>>(
        x, grid + offsets[L], out2, scales[L], hashmap_size - 1u,
        (unsigned)(L - NDENSE));
  }

  DCfg cfg;
  for (int i = 0; i < NDENSE; ++i) {
    cfg.lv[i].scale  = scales[i];
    cfg.lv[i].offset = offsets[i];
    cfg.lv[i].res    = ress[i];
  }
  kfinal_kernel<<<n_points / 32u, TPB, 0, stream>>>(x, grid, out2, cfg);
}